// Round 6
// baseline (171.199 us; speedup 1.0000x reference)
//
#include <hip/hip_runtime.h>
#include <hip/hip_bf16.h>

#define B_    4
#define C_    64
#define H_    192
#define W_    192
#define TAPS_ 9
#define MID_  12
#define HW_   (H_ * W_)
#define K_TOT 576                      // C_ * TAPS_
#define AT_STRIDE 72                   // bf16 elems per a_T row (8 chunks data + 1 pad chunk)

constexpr float STD_ = 0.47140452079103173f;  // sqrt(2)/3

using bf16 = __hip_bfloat16;
typedef __attribute__((ext_vector_type(4))) float  f32x4;
typedef __attribute__((ext_vector_type(8))) short  short8;

__device__ __forceinline__ unsigned short f2bf_bits(float v) {
    union { bf16 h; unsigned short u; } cv;
    cv.h = __float2bfloat16(v);   // RNE
    return cv.u;
}

// aT XOR swizzle: 16-B chunks within a row permuted by key=(row>>2)&7.
// Word-granular address (cw = word col 0..31; data only, pad chunk 8 untouched).
__device__ __forceinline__ int at_word(int row, int cw) {
    int key = (row >> 2) & 7;
    return row * (AT_STRIDE / 2) + ((((cw >> 2) ^ key) & 7) << 2) + (cw & 3);
}

// ---------------------------------------------------------------------------
// k_pre: fused {w2 repack -> bf16 [o][t*64+c]} (blocks 0..143) and
//        {x row partial sums} (blocks 144..911).
// ---------------------------------------------------------------------------
__global__ __launch_bounds__(256) void k_pre(const float* __restrict__ x,
                                             const float* __restrict__ w2,
                                             unsigned short* __restrict__ w2bf,
                                             float* __restrict__ partials) {
    int bx = blockIdx.x;
    if (bx < 144) {
        int d = bx * 256 + threadIdx.x;          // dest index, 36864 total
        int o = d / K_TOT;
        int rem = d - o * K_TOT;
        int t = rem >> 6;
        int c = rem & 63;
        w2bf[d] = f2bf_bits(w2[(o * C_ + c) * TAPS_ + t]);
        return;
    }
    bx -= 144;
    int bc = bx / 3, part = bx - 3 * (bx / 3);
    const float4* p = (const float4*)(x + (size_t)bc * HW_ + part * 12288);
    float s = 0.f;
    #pragma unroll
    for (int k = 0; k < 12; ++k) {
        float4 u = p[threadIdx.x + k * 256];
        s += u.x + u.y + u.z + u.w;
    }
    #pragma unroll
    for (int off = 32; off; off >>= 1) s += __shfl_down(s, off);
    __shared__ float red[4];
    if ((threadIdx.x & 63) == 0) red[threadIdx.x >> 6] = s;
    __syncthreads();
    if (threadIdx.x == 0)
        partials[bx] = red[0] + red[1] + red[2] + red[3];
}

// ---------------------------------------------------------------------------
// k_cf: reduce partials -> g; channel branch; FilterNorm -> cfn (B,C,9) f32.
// ---------------------------------------------------------------------------
__global__ __launch_bounds__(256) void k_cf(const float* __restrict__ partials,
                                            const float* __restrict__ cw1,
                                            const float* __restrict__ cb1,
                                            const float* __restrict__ cw2,
                                            const float* __restrict__ cb2,
                                            float* __restrict__ cfn) {
    __shared__ float g_l[B_ * C_];
    __shared__ float h1_l[B_ * MID_];
    int tid = threadIdx.x;
    g_l[tid] = (partials[tid * 3] + partials[tid * 3 + 1] + partials[tid * 3 + 2])
               * (1.0f / HW_);
    __syncthreads();
    if (tid < B_ * MID_) {
        int b = tid / MID_, m = tid % MID_;
        float acc = cb1[m];
        for (int c = 0; c < C_; ++c) acc += g_l[b * C_ + c] * cw1[m * C_ + c];
        h1_l[tid] = fmaxf(acc, 0.f);
    }
    __syncthreads();
    int b = tid >> 6, c = tid & 63;
    float f[TAPS_];
    float mean = 0.f;
    #pragma unroll
    for (int t = 0; t < TAPS_; ++t) {
        int n = c * TAPS_ + t;
        float acc = cb2[n];
        #pragma unroll
        for (int m = 0; m < MID_; ++m) acc += h1_l[b * MID_ + m] * cw2[n * MID_ + m];
        f[t] = acc;
        mean += acc;
    }
    mean *= (1.f / TAPS_);
    float var = 0.f;
    #pragma unroll
    for (int t = 0; t < TAPS_; ++t) { float d = f[t] - mean; var += d * d; }
    var *= (1.f / (TAPS_ - 1));
    float scale = STD_ / (sqrtf(fmaxf(var, 0.f)) + 1e-10f);
    #pragma unroll
    for (int t = 0; t < TAPS_; ++t)
        cfn[(b * C_ + c) * TAPS_ + t] = (f[t] - mean) * scale;
}

// ---------------------------------------------------------------------------
// k_main: one block per (b,h) row.
//   A: spatial filters -> s_l[k=w&3][t][w>>2] (conflict-free phase-B reads)
//   B: wave<->16ch, lane<->4 px (aligned float4 + 2 clamped edge scalars);
//      writes a_T bf16 with XOR-chunk swizzle (6-way instead of 24-way)
//   C: 1x9 conv as bf16 MFMA GEMM M=64 x N=192 x K=576; 9 A-frags preloaded
//      before phase A, rest prefetched at distance 2
// ---------------------------------------------------------------------------
__global__ __launch_bounds__(256, 4) void k_main(const float* __restrict__ x,
                                                 const float* __restrict__ sw,
                                                 const float* __restrict__ sb,
                                                 const float* __restrict__ cfn,
                                                 const unsigned short* __restrict__ w2bf,
                                                 const float* __restrict__ bias2,
                                                 float* __restrict__ out) {
    __shared__ __align__(16) char smem[36016];
    short*          aT   = (short*)smem;           // 200*72*2 = 28800 B
    unsigned*       aT32 = (unsigned*)smem;
    float*          sw_l = (float*)smem;           // alias (phase A only), 2304 B
    float*          s_l  = (float*)(smem + 28800); // 4*9*48*4 = 6912 B
    float*          b2_l = (float*)(smem + 35712); // 256 B
    float*          sb_l = (float*)(smem + 35968); // 40 B

    int bh = blockIdx.x;
    int bb = bh / H_;
    int h  = bh - bb * H_;
    int tid = threadIdx.x;
    int lane = tid & 63, wid = tid >> 6;
    int quad = lane >> 4, l16 = lane & 15;
    int obase = wid * 16;

    // ---- stage small tables ----
    for (int i = tid; i < TAPS_ * C_; i += 256) sw_l[i] = sw[i];
    if (tid < C_) b2_l[tid] = bias2[tid];
    if (tid < TAPS_) sb_l[tid] = sb[tid];
    __syncthreads();

    // ---- preload first 9 A-fragments (in flight across phases A+B) ----
    const short* w2s = (const short*)w2bf;
    const short* arow = w2s + (obase + l16) * K_TOT + quad * 8;
    short8 af[18];
    #pragma unroll
    for (int i = 0; i < 9; ++i) af[i] = *(const short8*)(arow + i * 32);

    // ---- Phase A: spatial filters ----
    if (tid < W_) {
        int w = tid;
        float acc[TAPS_];
        #pragma unroll
        for (int t = 0; t < TAPS_; ++t) acc[t] = sb_l[t];
        const float* px = x + (size_t)bb * C_ * HW_ + h * W_ + w;
        #pragma unroll 8
        for (int c = 0; c < C_; ++c) {
            float xv = px[(size_t)c * HW_];
            #pragma unroll
            for (int t = 0; t < TAPS_; ++t) acc[t] = fmaf(xv, sw_l[t * C_ + c], acc[t]);
        }
        float mean = 0.f;
        #pragma unroll
        for (int t = 0; t < TAPS_; ++t) mean += acc[t];
        mean *= (1.f / TAPS_);
        float var = 0.f;
        #pragma unroll
        for (int t = 0; t < TAPS_; ++t) { float d = acc[t] - mean; var += d * d; }
        var *= (1.f / (TAPS_ - 1));
        float scale = STD_ / (sqrtf(fmaxf(var, 0.f)) + 1e-10f);
        float* sp = s_l + (w & 3) * 432 + (w >> 2);
        #pragma unroll
        for (int t = 0; t < TAPS_; ++t) sp[t * 48] = (acc[t] - mean) * scale;
    }
    __syncthreads();   // phase B overwrites sw_l alias (aT) and reads s_l

    // ---- zero a_T halo rows (0..3 and 196..199); swizzle is a row-local
    //      permutation, so linear zeroing covers exactly the same words ----
    for (int i = tid; i < 8 * (AT_STRIDE / 2); i += 256) {
        int rowIdx = i / (AT_STRIDE / 2);
        int col    = i - rowIdx * (AT_STRIDE / 2);
        int r = (rowIdx < 4) ? rowIdx : (192 + rowIdx);
        aT32[r * (AT_STRIDE / 2) + col] = 0u;
    }

    // ---- Phase B: DDF apply + leaky -> a_T bf16 (swizzled) ----
    {
        int wbase = wid * 16;          // 16 channels per wave
        if (lane < 48) {
            int w0 = 4 * lane;         // 4 consecutive pixels per lane
            float sreg[4][TAPS_];      // conflict-free: word = 432k+48t+lane
            #pragma unroll
            for (int k = 0; k < 4; ++k) {
                const float* sp = s_l + k * 432 + lane;
                #pragma unroll
                for (int t = 0; t < TAPS_; ++t) sreg[k][t] = sp[t * 48];
            }
            bool l0 = (lane == 0), l47 = (lane == 47);
            int rok0 = (h > 0), rok2 = (h < H_ - 1);
            int midx = l0 ? 0 : (w0 - 1);        // clamped edge addresses
            int pidx = l47 ? w0 : (w0 + 4);
            const float* xbase = x + (long)bb * C_ * HW_ + (long)(h - 1) * W_;
            #pragma unroll 1
            for (int i = 0; i < 16; i += 2) {
                int c0 = wbase + i;
                int cu = __builtin_amdgcn_readfirstlane(c0);
                const float* cfp = cfn + bb * (C_ * TAPS_) + cu * TAPS_;
                const float* pc0 = xbase + (long)c0 * HW_;
                const float* pc1 = pc0 + HW_;
                float acc0[4] = {0.f, 0.f, 0.f, 0.f};
                float acc1[4] = {0.f, 0.f, 0.f, 0.f};
                #pragma unroll
                for (int r = 0; r < 3; ++r) {
                    if (r == 0 && !rok0) continue;   // block-uniform branches
                    if (r == 2 && !rok2) continue;
                    const float* p0 = pc0 + r * W_;
                    const float* p1 = pc1 + r * W_;
                    float4 fa = *(const float4*)(p0 + w0);   // 16B aligned
                    float4 fb = *(const float4*)(p1 + w0);
                    float ma = l0 ? 0.f : p0[midx];
                    float mb = l0 ? 0.f : p1[midx];
                    float pa = l47 ? 0.f : p0[pidx];
                    float pb = l47 ? 0.f : p1[pidx];
                    float va[6] = { ma, fa.x, fa.y, fa.z, fa.w, pa };
                    float vb[6] = { mb, fb.x, fb.y, fb.z, fb.w, pb };
                    #pragma unroll
                    for (int dc = 0; dc < 3; ++dc) {
                        int t = r * 3 + dc;
                        float cva = cfp[t];
                        float cvb = cfp[TAPS_ + t];
                        #pragma unroll
                        for (int k = 0; k < 4; ++k) {
                            acc0[k] = fmaf(va[k + dc] * sreg[k][t], cva, acc0[k]);
                            acc1[k] = fmaf(vb[k + dc] * sreg[k][t], cvb, acc1[k]);
                        }
                    }
                }
                int cw = c0 >> 1;                  // word col 0..31
                #pragma unroll
                for (int k = 0; k < 4; ++k) {
                    float a0 = acc0[k]; a0 = (a0 >= 0.f) ? a0 : 0.1f * a0;
                    float a1 = acc1[k]; a1 = (a1 >= 0.f) ? a1 : 0.1f * a1;
                    unsigned pk = (unsigned)f2bf_bits(a0)
                                | ((unsigned)f2bf_bits(a1) << 16);
                    aT32[at_word(w0 + k + 4, cw)] = pk;
                }
            }
        }
    }
    __syncthreads();

    // ---- Phase C: MFMA GEMM out[o][w] += A[o][q] * B[q][w], q = t*64 + c ----
    {
        f32x4 acc[12];
        #pragma unroll
        for (int n = 0; n < 12; ++n) acc[n] = (f32x4){0.f, 0.f, 0.f, 0.f};

        #pragma unroll
        for (int kk = 0; kk < 18; ++kk) {
            if (kk >= 7 && kk <= 15)   // prefetch af[9..17] at distance 2
                af[kk + 2] = *(const short8*)(arow + (kk + 2) * 32);
            int t = kk >> 1;
            int ch = ((kk & 1) << 2) + quad;     // 16-B chunk index 0..7
            int rowb = l16 + t;
            int key0 = (rowb >> 2) & 7;          // key(n) = key0 ^ (4*(n&1))
            int off0 = rowb * AT_STRIDE + (((ch ^ key0) & 7) << 3);
            int off1 = rowb * AT_STRIDE + (((ch ^ key0 ^ 4) & 7) << 3);
            #pragma unroll
            for (int n = 0; n < 12; ++n) {
                int off = ((n & 1) ? off1 : off0) + n * 16 * AT_STRIDE;
                short8 bf = *(const short8*)(aT + off);
                acc[n] = __builtin_amdgcn_mfma_f32_16x16x32_bf16(af[kk], bf, acc[n], 0, 0, 0);
            }
        }

        // epilogue: bias + residual add, C/D layout col=lane&15, row=quad*4+reg
        size_t xbase = (size_t)bb * C_ * HW_ + (size_t)h * W_;
        #pragma unroll
        for (int n = 0; n < 12; ++n) {
            int w = n * 16 + l16;
            #pragma unroll
            for (int reg = 0; reg < 4; ++reg) {
                int o = obase + quad * 4 + reg;
                size_t idx = xbase + (size_t)o * HW_ + w;
                out[idx] = acc[n][reg] + b2_l[o] + x[idx];
            }
        }
    }
}

// ---------------------------------------------------------------------------
extern "C" void kernel_launch(void* const* d_in, const int* in_sizes, int n_in,
                              void* d_out, int out_size, void* d_ws, size_t ws_size,
                              hipStream_t stream) {
    const float* x   = (const float*)d_in[0];
    const float* sw  = (const float*)d_in[1];
    const float* sb  = (const float*)d_in[2];
    const float* cw1 = (const float*)d_in[3];
    const float* cb1 = (const float*)d_in[4];
    const float* cw2 = (const float*)d_in[5];
    const float* cb2 = (const float*)d_in[6];
    const float* w2  = (const float*)d_in[7];
    const float* b2  = (const float*)d_in[8];
    float* out = (float*)d_out;

    unsigned short* w2bf = (unsigned short*)d_ws;                 // 73728 B
    float* partials = (float*)((char*)d_ws + 73728);              // 3072 B
    float* cfn      = (float*)((char*)d_ws + 76800);              // 9216 B

    hipLaunchKernelGGL(k_pre, dim3(912), dim3(256), 0, stream, x, w2, w2bf, partials);
    hipLaunchKernelGGL(k_cf, dim3(1), dim3(256), 0, stream,
                       partials, cw1, cb1, cw2, cb2, cfn);
    hipLaunchKernelGGL(k_main, dim3(B_ * H_), dim3(256), 0, stream,
                       x, sw, sb, cfn, w2bf, b2, out);
}

// Round 7
// 147.871 us; speedup vs baseline: 1.1578x; 1.1578x over previous
//
#include <hip/hip_runtime.h>
#include <hip/hip_bf16.h>

#define B_    4
#define C_    64
#define H_    192
#define W_    192
#define TAPS_ 9
#define MID_  12
#define HW_   (H_ * W_)
#define K_TOT 576                      // C_ * TAPS_
#define AT_STRIDE 72                   // bf16 elems per a_T row (8 chunks data + 1 pad chunk)

constexpr float STD_ = 0.47140452079103173f;  // sqrt(2)/3

using bf16 = __hip_bfloat16;
typedef __attribute__((ext_vector_type(4))) float  f32x4;
typedef __attribute__((ext_vector_type(8))) short  short8;

__device__ __forceinline__ unsigned short f2bf_bits(float v) {
    union { bf16 h; unsigned short u; } cv;
    cv.h = __float2bfloat16(v);   // RNE
    return cv.u;
}

// aT XOR swizzle: 16-B chunks within a row permuted by key=(row>>2)&7.
// Word-granular address (cw = word col 0..31; data only, pad chunk 8 untouched).
__device__ __forceinline__ int at_word(int row, int cw) {
    int key = (row >> 2) & 7;
    return row * (AT_STRIDE / 2) + ((((cw >> 2) ^ key) & 7) << 2) + (cw & 3);
}

// ---------------------------------------------------------------------------
// k_pre: fused {w2 repack -> bf16 [o][t*64+c]} (blocks 0..143) and
//        {x row partial sums} (blocks 144..911).
// ---------------------------------------------------------------------------
__global__ __launch_bounds__(256) void k_pre(const float* __restrict__ x,
                                             const float* __restrict__ w2,
                                             unsigned short* __restrict__ w2bf,
                                             float* __restrict__ partials) {
    int bx = blockIdx.x;
    if (bx < 144) {
        int d = bx * 256 + threadIdx.x;          // dest index, 36864 total
        int o = d / K_TOT;
        int rem = d - o * K_TOT;
        int t = rem >> 6;
        int c = rem & 63;
        w2bf[d] = f2bf_bits(w2[(o * C_ + c) * TAPS_ + t]);
        return;
    }
    bx -= 144;
    int bc = bx / 3, part = bx - 3 * (bx / 3);
    const float4* p = (const float4*)(x + (size_t)bc * HW_ + part * 12288);
    float s = 0.f;
    #pragma unroll
    for (int k = 0; k < 12; ++k) {
        float4 u = p[threadIdx.x + k * 256];
        s += u.x + u.y + u.z + u.w;
    }
    #pragma unroll
    for (int off = 32; off; off >>= 1) s += __shfl_down(s, off);
    __shared__ float red[4];
    if ((threadIdx.x & 63) == 0) red[threadIdx.x >> 6] = s;
    __syncthreads();
    if (threadIdx.x == 0)
        partials[bx] = red[0] + red[1] + red[2] + red[3];
}

// ---------------------------------------------------------------------------
// k_cf: reduce partials -> g; channel branch; FilterNorm -> cfn (B,C,9) f32.
// ---------------------------------------------------------------------------
__global__ __launch_bounds__(256) void k_cf(const float* __restrict__ partials,
                                            const float* __restrict__ cw1,
                                            const float* __restrict__ cb1,
                                            const float* __restrict__ cw2,
                                            const float* __restrict__ cb2,
                                            float* __restrict__ cfn) {
    __shared__ float g_l[B_ * C_];
    __shared__ float h1_l[B_ * MID_];
    int tid = threadIdx.x;
    g_l[tid] = (partials[tid * 3] + partials[tid * 3 + 1] + partials[tid * 3 + 2])
               * (1.0f / HW_);
    __syncthreads();
    if (tid < B_ * MID_) {
        int b = tid / MID_, m = tid % MID_;
        float acc = cb1[m];
        for (int c = 0; c < C_; ++c) acc += g_l[b * C_ + c] * cw1[m * C_ + c];
        h1_l[tid] = fmaxf(acc, 0.f);
    }
    __syncthreads();
    int b = tid >> 6, c = tid & 63;
    float f[TAPS_];
    float mean = 0.f;
    #pragma unroll
    for (int t = 0; t < TAPS_; ++t) {
        int n = c * TAPS_ + t;
        float acc = cb2[n];
        #pragma unroll
        for (int m = 0; m < MID_; ++m) acc += h1_l[b * MID_ + m] * cw2[n * MID_ + m];
        f[t] = acc;
        mean += acc;
    }
    mean *= (1.f / TAPS_);
    float var = 0.f;
    #pragma unroll
    for (int t = 0; t < TAPS_; ++t) { float d = f[t] - mean; var += d * d; }
    var *= (1.f / (TAPS_ - 1));
    float scale = STD_ / (sqrtf(fmaxf(var, 0.f)) + 1e-10f);
    #pragma unroll
    for (int t = 0; t < TAPS_; ++t)
        cfn[(b * C_ + c) * TAPS_ + t] = (f[t] - mean) * scale;
}

// ---------------------------------------------------------------------------
// k_main: one block per (b,h) row.
//   A: spatial filters -> s_l[k=w&3][t][w>>2] (conflict-free phase-B reads)
//   B: wave<->16ch, lane<->4 px (aligned float4 + 2 clamped edge scalars);
//      writes a_T bf16 with XOR-chunk swizzle
//   C: 1x9 conv as bf16 MFMA GEMM M=64 x N=192 x K=576; A-frags streamed
//      through a rolling 3-register window (no spills), distance-2 prefetch
// ---------------------------------------------------------------------------
__global__ __launch_bounds__(256, 3) void k_main(const float* __restrict__ x,
                                                 const float* __restrict__ sw,
                                                 const float* __restrict__ sb,
                                                 const float* __restrict__ cfn,
                                                 const unsigned short* __restrict__ w2bf,
                                                 const float* __restrict__ bias2,
                                                 float* __restrict__ out) {
    __shared__ __align__(16) char smem[36016];
    short*          aT   = (short*)smem;           // 200*72*2 = 28800 B
    unsigned*       aT32 = (unsigned*)smem;
    float*          sw_l = (float*)smem;           // alias (phase A only), 2304 B
    float*          s_l  = (float*)(smem + 28800); // 4*9*48*4 = 6912 B
    float*          b2_l = (float*)(smem + 35712); // 256 B
    float*          sb_l = (float*)(smem + 35968); // 40 B

    int bh = blockIdx.x;
    int bb = bh / H_;
    int h  = bh - bb * H_;
    int tid = threadIdx.x;
    int lane = tid & 63, wid = tid >> 6;
    int quad = lane >> 4, l16 = lane & 15;
    int obase = wid * 16;

    // ---- stage small tables ----
    for (int i = tid; i < TAPS_ * C_; i += 256) sw_l[i] = sw[i];
    if (tid < C_) b2_l[tid] = bias2[tid];
    if (tid < TAPS_) sb_l[tid] = sb[tid];
    __syncthreads();

    // ---- preload first 2 A-fragments (8 VGPRs, in flight across A+B) ----
    const short* w2s = (const short*)w2bf;
    const short* arow = w2s + (obase + l16) * K_TOT + quad * 8;
    short8 a0 = *(const short8*)(arow);
    short8 a1 = *(const short8*)(arow + 32);

    // ---- Phase A: spatial filters ----
    if (tid < W_) {
        int w = tid;
        float acc[TAPS_];
        #pragma unroll
        for (int t = 0; t < TAPS_; ++t) acc[t] = sb_l[t];
        const float* px = x + (size_t)bb * C_ * HW_ + h * W_ + w;
        #pragma unroll 8
        for (int c = 0; c < C_; ++c) {
            float xv = px[(size_t)c * HW_];
            #pragma unroll
            for (int t = 0; t < TAPS_; ++t) acc[t] = fmaf(xv, sw_l[t * C_ + c], acc[t]);
        }
        float mean = 0.f;
        #pragma unroll
        for (int t = 0; t < TAPS_; ++t) mean += acc[t];
        mean *= (1.f / TAPS_);
        float var = 0.f;
        #pragma unroll
        for (int t = 0; t < TAPS_; ++t) { float d = acc[t] - mean; var += d * d; }
        var *= (1.f / (TAPS_ - 1));
        float scale = STD_ / (sqrtf(fmaxf(var, 0.f)) + 1e-10f);
        float* sp = s_l + (w & 3) * 432 + (w >> 2);
        #pragma unroll
        for (int t = 0; t < TAPS_; ++t) sp[t * 48] = (acc[t] - mean) * scale;
    }
    __syncthreads();   // phase B overwrites sw_l alias (aT) and reads s_l

    // ---- zero a_T halo rows (0..3 and 196..199); swizzle is a row-local
    //      permutation, so linear zeroing covers exactly the same words ----
    for (int i = tid; i < 8 * (AT_STRIDE / 2); i += 256) {
        int rowIdx = i / (AT_STRIDE / 2);
        int col    = i - rowIdx * (AT_STRIDE / 2);
        int r = (rowIdx < 4) ? rowIdx : (192 + rowIdx);
        aT32[r * (AT_STRIDE / 2) + col] = 0u;
    }

    // ---- Phase B: DDF apply + leaky -> a_T bf16 (swizzled) ----
    {
        int wbase = wid * 16;          // 16 channels per wave
        if (lane < 48) {
            int w0 = 4 * lane;         // 4 consecutive pixels per lane
            float sreg[4][TAPS_];      // conflict-free: word = 432k+48t+lane
            #pragma unroll
            for (int k = 0; k < 4; ++k) {
                const float* sp = s_l + k * 432 + lane;
                #pragma unroll
                for (int t = 0; t < TAPS_; ++t) sreg[k][t] = sp[t * 48];
            }
            bool l0 = (lane == 0), l47 = (lane == 47);
            int rok0 = (h > 0), rok2 = (h < H_ - 1);
            int midx = l0 ? 0 : (w0 - 1);        // clamped edge addresses
            int pidx = l47 ? w0 : (w0 + 4);
            const float* xbase = x + (long)bb * C_ * HW_ + (long)(h - 1) * W_;
            #pragma unroll 1
            for (int i = 0; i < 16; i += 2) {
                int c0 = wbase + i;
                int cu = __builtin_amdgcn_readfirstlane(c0);
                const float* cfp = cfn + bb * (C_ * TAPS_) + cu * TAPS_;
                const float* pc0 = xbase + (long)c0 * HW_;
                const float* pc1 = pc0 + HW_;
                float acc0[4] = {0.f, 0.f, 0.f, 0.f};
                float acc1[4] = {0.f, 0.f, 0.f, 0.f};
                #pragma unroll
                for (int r = 0; r < 3; ++r) {
                    if (r == 0 && !rok0) continue;   // block-uniform branches
                    if (r == 2 && !rok2) continue;
                    const float* p0 = pc0 + r * W_;
                    const float* p1 = pc1 + r * W_;
                    float4 fa = *(const float4*)(p0 + w0);   // 16B aligned
                    float4 fb = *(const float4*)(p1 + w0);
                    float ma = l0 ? 0.f : p0[midx];
                    float mb = l0 ? 0.f : p1[midx];
                    float pa = l47 ? 0.f : p0[pidx];
                    float pb = l47 ? 0.f : p1[pidx];
                    float va[6] = { ma, fa.x, fa.y, fa.z, fa.w, pa };
                    float vb[6] = { mb, fb.x, fb.y, fb.z, fb.w, pb };
                    #pragma unroll
                    for (int dc = 0; dc < 3; ++dc) {
                        int t = r * 3 + dc;
                        float cva = cfp[t];
                        float cvb = cfp[TAPS_ + t];
                        #pragma unroll
                        for (int k = 0; k < 4; ++k) {
                            acc0[k] = fmaf(va[k + dc] * sreg[k][t], cva, acc0[k]);
                            acc1[k] = fmaf(vb[k + dc] * sreg[k][t], cvb, acc1[k]);
                        }
                    }
                }
                int cw = c0 >> 1;                  // word col 0..31
                #pragma unroll
                for (int k = 0; k < 4; ++k) {
                    float a0v = acc0[k]; a0v = (a0v >= 0.f) ? a0v : 0.1f * a0v;
                    float a1v = acc1[k]; a1v = (a1v >= 0.f) ? a1v : 0.1f * a1v;
                    unsigned pk = (unsigned)f2bf_bits(a0v)
                                | ((unsigned)f2bf_bits(a1v) << 16);
                    aT32[at_word(w0 + k + 4, cw)] = pk;
                }
            }
        }
    }
    __syncthreads();

    // ---- Phase C: MFMA GEMM out[o][w] += A[o][q] * B[q][w], q = t*64 + c ----
    {
        f32x4 acc[12];
        #pragma unroll
        for (int n = 0; n < 12; ++n) acc[n] = (f32x4){0.f, 0.f, 0.f, 0.f};

        #pragma unroll 1
        for (int kk = 0; kk < 18; ++kk) {
            short8 a2 = a1;
            if (kk < 16) a2 = *(const short8*)(arow + (kk + 2) * 32);  // dist-2 stream
            int t = kk >> 1;
            int ch = ((kk & 1) << 2) + quad;     // 16-B chunk index 0..7
            int rowb = l16 + t;
            int key0 = (rowb >> 2) & 7;          // key(n) = key0 ^ (4*(n&1))
            int off0 = rowb * AT_STRIDE + (((ch ^ key0) & 7) << 3);
            int off1 = rowb * AT_STRIDE + (((ch ^ key0 ^ 4) & 7) << 3);
            #pragma unroll
            for (int n = 0; n < 12; ++n) {
                int off = ((n & 1) ? off1 : off0) + n * 16 * AT_STRIDE;
                short8 bf = *(const short8*)(aT + off);
                acc[n] = __builtin_amdgcn_mfma_f32_16x16x32_bf16(a0, bf, acc[n], 0, 0, 0);
            }
            a0 = a1; a1 = a2;
        }

        // epilogue: bias + residual add, C/D layout col=lane&15, row=quad*4+reg
        size_t xbase = (size_t)bb * C_ * HW_ + (size_t)h * W_;
        #pragma unroll
        for (int n = 0; n < 12; ++n) {
            int w = n * 16 + l16;
            #pragma unroll
            for (int reg = 0; reg < 4; ++reg) {
                int o = obase + quad * 4 + reg;
                size_t idx = xbase + (size_t)o * HW_ + w;
                out[idx] = acc[n][reg] + b2_l[o] + x[idx];
            }
        }
    }
}

// ---------------------------------------------------------------------------
extern "C" void kernel_launch(void* const* d_in, const int* in_sizes, int n_in,
                              void* d_out, int out_size, void* d_ws, size_t ws_size,
                              hipStream_t stream) {
    const float* x   = (const float*)d_in[0];
    const float* sw  = (const float*)d_in[1];
    const float* sb  = (const float*)d_in[2];
    const float* cw1 = (const float*)d_in[3];
    const float* cb1 = (const float*)d_in[4];
    const float* cw2 = (const float*)d_in[5];
    const float* cb2 = (const float*)d_in[6];
    const float* w2  = (const float*)d_in[7];
    const float* b2  = (const float*)d_in[8];
    float* out = (float*)d_out;

    unsigned short* w2bf = (unsigned short*)d_ws;                 // 73728 B
    float* partials = (float*)((char*)d_ws + 73728);              // 3072 B
    float* cfn      = (float*)((char*)d_ws + 76800);              // 9216 B

    hipLaunchKernelGGL(k_pre, dim3(912), dim3(256), 0, stream, x, w2, w2bf, partials);
    hipLaunchKernelGGL(k_cf, dim3(1), dim3(256), 0, stream,
                       partials, cw1, cb1, cw2, cb2, cfn);
    hipLaunchKernelGGL(k_main, dim3(B_ * H_), dim3(256), 0, stream,
                       x, sw, sb, cfn, w2bf, b2, out);
}